// Round 15
// baseline (75.767 us; speedup 1.0000x reference)
//
#include <hip/hip_runtime.h>

#define BATCH 256
#define ZTILE 8           // z per LDS tile
#define TPB 8             // tiles per block -> 64 z per block; grid.y = 4
#define PADF 12           // floats per stripe (8 z + 4 pad) = 48 B
#define CAP 4             // register entry slots (tail loop beyond)
#define DIN_CAP 416       // dim_in for this problem

// ---------------- prep: tiled transpose f->fT + COO segment-bounds scatter ----
__global__ __launch_bounds__(256) void prep_t(
    const float* __restrict__ f, const int* __restrict__ rows,
    int* __restrict__ rstart, int* __restrict__ rend,
    float* __restrict__ fT, int nnz, int dim_in, int TB, int ctiles)
{
    const int bx = blockIdx.x;
    if (bx < TB) {
        __shared__ float lt[32][33];
        const int c0 = (bx % ctiles) * 32;
        const int z0 = (bx / ctiles) * 32;
        const int ic = threadIdx.x & 31;
        const int i0 = threadIdx.x >> 5;
#pragma unroll
        for (int k = 0; k < 4; ++k) {
            const int a = i0 + 8 * k;
            const int c = c0 + ic;
            lt[a][ic] = (c < dim_in) ? f[(size_t)(z0 + a) * dim_in + c] : 0.0f;
        }
        __syncthreads();
#pragma unroll
        for (int k = 0; k < 4; ++k) {
            const int b = i0 + 8 * k;
            const int c = c0 + b;
            if (c < dim_in)
                fT[(size_t)c * BATCH + z0 + ic] = lt[ic][b];
        }
    } else {
        const int e = (bx - TB) * 256 + threadIdx.x;
        if (e < nnz) {
            const int r = rows[e];
            if (e == 0 || rows[e - 1] != r) rstart[r] = e;
            if (e == nnz - 1 || rows[e + 1] != r) rend[r] = e + 1;
        }
    }
}

// Barrier waiting only on LDS ops; global loads/stores stay in flight.
__device__ __forceinline__ void lds_sync()
{
    asm volatile("s_waitcnt lgkmcnt(0)" ::: "memory");
    __builtin_amdgcn_sched_barrier(0);
    __builtin_amdgcn_s_barrier();
    __builtin_amdgcn_sched_barrier(0);
}

// Double-buffered pipeline: issue stage(t+1) -> compute(t) -> ds_write(t+1)
// -> ONE lgkm-barrier per tile. Staging latency hides under compute.
__global__ __launch_bounds__(256) void tsq_pipe(
    const float* __restrict__ fT, const float* __restrict__ vals,
    const int* __restrict__ ci, const int* __restrict__ cj,
    const int* __restrict__ rstart, const int* __restrict__ rend,
    float* __restrict__ out, int dim_in, int dim_out, int nnz)
{
    __shared__ __align__(16) float fz[2][DIN_CAP * PADF];   // 2 x 19968 B -> 4 blocks/CU

    const int tid = threadIdx.x;
    const int r   = blockIdx.x * 256 + tid;
    const bool valid = (r < dim_out);

    // bounds from scatter; untouched rows hold 0xAA poison -> reject
    int s = 0, e1 = 0;
    if (valid) {
        const int ss = rstart[r];
        const int ee = rend[r];
        if (ss >= 0 && ee > ss && ee <= nnz) { s = ss; e1 = ee; }
    }
    const int cnt  = e1 - s;
    const int creg = cnt < CAP ? cnt : CAP;

    int pa_[CAP]; int pb_[CAP]; float pv_[CAP];
#pragma unroll
    for (int i = 0; i < CAP; ++i) {
        if (i < creg) {
            pa_[i] = ci[s + i] * (PADF * 4);
            pb_[i] = cj[s + i] * (PADF * 4);
            pv_[i] = vals[s + i];
        } else { pa_[i] = 0; pb_[i] = 0; pv_[i] = 0.f; }
    }

    const int zbase  = blockIdx.y * (ZTILE * TPB);
    const int nchunk = dim_in * (ZTILE / 4);       // 832 float4 chunks per tile

    // chunk assignment: thread handles chunks tid, tid+256, ... (<=4)
    float4 rg[4];
    int    cc[4];   // chunk index; -1 if none
#pragma unroll
    for (int k = 0; k < 4; ++k) cc[k] = (tid + k * 256 < nchunk) ? tid + k * 256 : -1;

    // ---- prologue: stage tile 0 into buf 0
#pragma unroll
    for (int k = 0; k < 4; ++k) {
        if (cc[k] >= 0) {
            const int c  = cc[k] >> 1;
            const int zq = cc[k] & 1;
            rg[k] = *(const float4*)(fT + (size_t)c * BATCH + zbase + zq * 4);
        }
    }
#pragma unroll
    for (int k = 0; k < 4; ++k) {
        if (cc[k] >= 0) {
            const int c  = cc[k] >> 1;
            const int zq = cc[k] & 1;
            *(float4*)(&fz[0][c * PADF + zq * 4]) = rg[k];
        }
    }
    lds_sync();

    int cur = 0;
    for (int t = 0; t < TPB; ++t) {
        const int z0 = zbase + t * ZTILE;

        // ---- issue next tile's global loads (latency hidden under compute)
        if (t + 1 < TPB) {
            const int zn = z0 + ZTILE;
#pragma unroll
            for (int k = 0; k < 4; ++k) {
                if (cc[k] >= 0) {
                    const int c  = cc[k] >> 1;
                    const int zq = cc[k] & 1;
                    rg[k] = *(const float4*)(fT + (size_t)c * BATCH + zn + zq * 4);
                }
            }
        }

        // ---- compute 8 z from fz[cur]
        const char* fb = (const char*)fz[cur];
        float4 a0 = {0,0,0,0}, a1 = {0,0,0,0};
#pragma unroll
        for (int i = 0; i < CAP; ++i) {
            if (i < creg) {
                const float v = pv_[i];
                const char* ba = fb + pa_[i];
                const char* bb = fb + pb_[i];
                float4 xa, xb;
                xa = *(const float4*)(ba);      xb = *(const float4*)(bb);
                a0.x += v*xa.x*xb.x; a0.y += v*xa.y*xb.y; a0.z += v*xa.z*xb.z; a0.w += v*xa.w*xb.w;
                xa = *(const float4*)(ba + 16); xb = *(const float4*)(bb + 16);
                a1.x += v*xa.x*xb.x; a1.y += v*xa.y*xb.y; a1.z += v*xa.z*xb.z; a1.w += v*xa.w*xb.w;
            }
        }
        for (int e = s + CAP; e < e1; ++e) {   // rare long rows
            const int a = ci[e], b = cj[e]; const float v = vals[e];
            const char* ba = fb + a * (PADF * 4);
            const char* bb = fb + b * (PADF * 4);
            float4 xa, xb;
            xa = *(const float4*)(ba);      xb = *(const float4*)(bb);
            a0.x += v*xa.x*xb.x; a0.y += v*xa.y*xb.y; a0.z += v*xa.z*xb.z; a0.w += v*xa.w*xb.w;
            xa = *(const float4*)(ba + 16); xb = *(const float4*)(bb + 16);
            a1.x += v*xa.x*xb.x; a1.y += v*xa.y*xb.y; a1.z += v*xa.z*xb.z; a1.w += v*xa.w*xb.w;
        }

        if (valid) {   // 8 coalesced nt stores; stay in flight across barrier
            float* o = out + (size_t)z0 * dim_out + r;
            const size_t d = dim_out;
            __builtin_nontemporal_store(a0.x, o);        __builtin_nontemporal_store(a0.y, o + d);
            __builtin_nontemporal_store(a0.z, o + 2*d);  __builtin_nontemporal_store(a0.w, o + 3*d);
            __builtin_nontemporal_store(a1.x, o + 4*d);  __builtin_nontemporal_store(a1.y, o + 5*d);
            __builtin_nontemporal_store(a1.z, o + 6*d);  __builtin_nontemporal_store(a1.w, o + 7*d);
        }

        // ---- write next tile into the other buffer (vmcnt wait auto-inserted)
        if (t + 1 < TPB) {
#pragma unroll
            for (int k = 0; k < 4; ++k) {
                if (cc[k] >= 0) {
                    const int c  = cc[k] >> 1;
                    const int zq = cc[k] & 1;
                    *(float4*)(&fz[cur ^ 1][c * PADF + zq * 4]) = rg[k];
                }
            }
        }
        lds_sync();   // single barrier per tile: lgkm only, no store drain
        cur ^= 1;
    }
}

// Fallback: reads f directly, one z per block.y.
__global__ __launch_bounds__(256) void tsq_fallback(
    const float* __restrict__ f, const float* __restrict__ vals,
    const int* __restrict__ ci, const int* __restrict__ cj,
    const int* __restrict__ rstart, const int* __restrict__ rend,
    float* __restrict__ out, int dim_in, int dim_out, int nnz)
{
    const int r = blockIdx.x * blockDim.x + threadIdx.x;
    if (r >= dim_out) return;
    const int z = blockIdx.y;
    const float* __restrict__ fb = f + (size_t)z * dim_in;
    const int ss = rstart[r];
    const int ee = rend[r];
    float acc = 0.0f;
    if (ss >= 0 && ee > ss && ee <= nnz) {
        for (int e = ss; e < ee; ++e)
            acc += vals[e] * fb[ci[e]] * fb[cj[e]];
    }
    out[(size_t)z * dim_out + r] = acc;
}

extern "C" void kernel_launch(void* const* d_in, const int* in_sizes, int n_in,
                              void* d_out, int out_size, void* d_ws, size_t ws_size,
                              hipStream_t stream)
{
    const float* f    = (const float*)d_in[0];
    const float* vals = (const float*)d_in[1];
    const int*   rows = (const int*)d_in[2];
    const int*   ci   = (const int*)d_in[3];
    const int*   cj   = (const int*)d_in[4];
    float*       out  = (float*)d_out;

    const int nnz     = in_sizes[1];
    const int nF      = in_sizes[0];
    const int dim_in  = nF / BATCH;
    const int dim_out = out_size / BATCH;

    int*   rstart = (int*)d_ws;
    int*   rend   = rstart + dim_out;
    float* fT     = (float*)(rend + dim_out);

    const int use_main = (dim_in <= DIN_CAP) &&
                         (ws_size >= (size_t)(2 * dim_out) * 4 + (size_t)nF * 4);

    const int ctiles = (dim_in + 31) / 32;
    const int TB = use_main ? ctiles * (BATCH / 32) : 0;
    const int NB = (nnz + 255) / 256;
    prep_t<<<TB + NB, 256, 0, stream>>>(f, rows, rstart, rend, fT,
                                        nnz, dim_in, TB, ctiles);

    if (use_main) {
        dim3 grid((dim_out + 255) / 256, BATCH / (ZTILE * TPB));
        tsq_pipe<<<grid, 256, 0, stream>>>(fT, vals, ci, cj, rstart, rend, out,
                                           dim_in, dim_out, nnz);
    } else {
        dim3 grid((dim_out + 255) / 256, BATCH);
        tsq_fallback<<<grid, 256, 0, stream>>>(f, vals, ci, cj, rstart, rend,
                                               out, dim_in, dim_out, nnz);
    }
}

// Round 16
// 36.814 us; speedup vs baseline: 2.0581x; 2.0581x over previous
//
#include <hip/hip_runtime.h>

#define BATCH 256
#define ZTILE 16          // z per LDS tile (16 tiles total)
#define YSPLIT 3          // grid.y; block loops tiles t = y, y+3, ...
#define PADF 20           // floats per stripe (16 z + 4 pad) = 80 B
#define DIN_CAP 416       // dim_in for this problem

// ---------------- prep: tiled transpose f->fT + COO segment-bounds scatter ----
__global__ __launch_bounds__(256) void prep_t(
    const float* __restrict__ f, const int* __restrict__ rows,
    int* __restrict__ rstart, int* __restrict__ rend,
    float* __restrict__ fT, int nnz, int dim_in, int TB, int ctiles)
{
    const int bx = blockIdx.x;
    if (bx < TB) {
        __shared__ float lt[32][33];
        const int c0 = (bx % ctiles) * 32;
        const int z0 = (bx / ctiles) * 32;
        const int ic = threadIdx.x & 31;
        const int i0 = threadIdx.x >> 5;
#pragma unroll
        for (int k = 0; k < 4; ++k) {
            const int a = i0 + 8 * k;
            const int c = c0 + ic;
            lt[a][ic] = (c < dim_in) ? f[(size_t)(z0 + a) * dim_in + c] : 0.0f;
        }
        __syncthreads();
#pragma unroll
        for (int k = 0; k < 4; ++k) {
            const int b = i0 + 8 * k;
            const int c = c0 + b;
            if (c < dim_in)
                fT[(size_t)c * BATCH + z0 + ic] = lt[ic][b];
        }
    } else {
        const int e = (bx - TB) * 256 + threadIdx.x;
        if (e < nnz) {
            const int r = rows[e];
            if (e == 0 || rows[e - 1] != r) rstart[r] = e;
            if (e == nnz - 1 || rows[e + 1] != r) rend[r] = e + 1;
        }
    }
}

// Barrier that waits only on LDS ops, leaving global stores in flight.
__device__ __forceinline__ void lds_sync()
{
    asm volatile("s_waitcnt lgkmcnt(0)" ::: "memory");
    __builtin_amdgcn_sched_barrier(0);
    __builtin_amdgcn_s_barrier();
    __builtin_amdgcn_sched_barrier(0);
}

// R9 structure; NORMAL stores (L2 write-combining) + single-generation grid.
__global__ __launch_bounds__(256) void tsq_main(
    const float* __restrict__ fT, const float* __restrict__ vals,
    const int* __restrict__ ci, const int* __restrict__ cj,
    const int* __restrict__ rstart, const int* __restrict__ rend,
    float* __restrict__ out, int dim_in, int dim_out, int nnz)
{
    __shared__ __align__(16) float fzT[DIN_CAP * PADF];   // 33280 B -> 4 blocks/CU

    const int r = blockIdx.x * 256 + threadIdx.x;
    const bool valid = (r < dim_out);

    // bounds from scatter; untouched rows hold 0xAA poison -> reject
    int s = 0, e1 = 0;
    if (valid) {
        const int ss = rstart[r];
        const int ee = rend[r];
        if (ss >= 0 && ee > ss && ee <= nnz) { s = ss; e1 = ee; }
    }

    const int nchunk = dim_in * (ZTILE / 4);
    const int ntile  = BATCH / ZTILE;          // 16

    for (int t = blockIdx.y; t < ntile; t += YSPLIT) {
        const int z0 = t * ZTILE;

        // stage fzT[c][0..15] = fT[c][z0..z0+15]; float4 both sides
        for (int i = threadIdx.x; i < nchunk; i += 256) {
            const int c  = i >> 2;
            const int zq = i & 3;
            const float4 v = *(const float4*)(fT + (size_t)c * BATCH + z0 + zq * 4);
            *(float4*)(fzT + c * PADF + zq * 4) = v;
        }
        lds_sync();   // staging visible; previous tile's stores stay in flight

        float4 a0 = {0,0,0,0}, a1 = {0,0,0,0}, a2 = {0,0,0,0}, a3 = {0,0,0,0};
        for (int e = s; e < e1; ++e) {
            const int   a = ci[e];
            const int   b = cj[e];
            const float v = vals[e];
            const float* ba = fzT + a * PADF;
            const float* bb = fzT + b * PADF;
            float4 xa, xb;
            xa = *(const float4*)(ba);      xb = *(const float4*)(bb);
            a0.x += v*xa.x*xb.x; a0.y += v*xa.y*xb.y; a0.z += v*xa.z*xb.z; a0.w += v*xa.w*xb.w;
            xa = *(const float4*)(ba + 4);  xb = *(const float4*)(bb + 4);
            a1.x += v*xa.x*xb.x; a1.y += v*xa.y*xb.y; a1.z += v*xa.z*xb.z; a1.w += v*xa.w*xb.w;
            xa = *(const float4*)(ba + 8);  xb = *(const float4*)(bb + 8);
            a2.x += v*xa.x*xb.x; a2.y += v*xa.y*xb.y; a2.z += v*xa.z*xb.z; a2.w += v*xa.w*xb.w;
            xa = *(const float4*)(ba + 12); xb = *(const float4*)(bb + 12);
            a3.x += v*xa.x*xb.x; a3.y += v*xa.y*xb.y; a3.z += v*xa.z*xb.z; a3.w += v*xa.w*xb.w;
        }

        if (valid) {   // 16 coalesced NORMAL stores (L2-buffered)
            float* o = out + (size_t)z0 * dim_out + r;
            const size_t d = dim_out;
            o[0]      = a0.x;  o[d]      = a0.y;  o[2*d]  = a0.z;  o[3*d]  = a0.w;
            o[4*d]    = a1.x;  o[5*d]    = a1.y;  o[6*d]  = a1.z;  o[7*d]  = a1.w;
            o[8*d]    = a2.x;  o[9*d]    = a2.y;  o[10*d] = a2.z;  o[11*d] = a2.w;
            o[12*d]   = a3.x;  o[13*d]   = a3.y;  o[14*d] = a3.z;  o[15*d] = a3.w;
        }
        lds_sync();   // ds_reads complete -> safe to restage
    }
}

// Fallback: reads f directly, one z per block.y.
__global__ __launch_bounds__(256) void tsq_fallback(
    const float* __restrict__ f, const float* __restrict__ vals,
    const int* __restrict__ ci, const int* __restrict__ cj,
    const int* __restrict__ rstart, const int* __restrict__ rend,
    float* __restrict__ out, int dim_in, int dim_out, int nnz)
{
    const int r = blockIdx.x * blockDim.x + threadIdx.x;
    if (r >= dim_out) return;
    const int z = blockIdx.y;
    const float* __restrict__ fb = f + (size_t)z * dim_in;
    const int ss = rstart[r];
    const int ee = rend[r];
    float acc = 0.0f;
    if (ss >= 0 && ee > ss && ee <= nnz) {
        for (int e = ss; e < ee; ++e)
            acc += vals[e] * fb[ci[e]] * fb[cj[e]];
    }
    out[(size_t)z * dim_out + r] = acc;
}

extern "C" void kernel_launch(void* const* d_in, const int* in_sizes, int n_in,
                              void* d_out, int out_size, void* d_ws, size_t ws_size,
                              hipStream_t stream)
{
    const float* f    = (const float*)d_in[0];
    const float* vals = (const float*)d_in[1];
    const int*   rows = (const int*)d_in[2];
    const int*   ci   = (const int*)d_in[3];
    const int*   cj   = (const int*)d_in[4];
    float*       out  = (float*)d_out;

    const int nnz     = in_sizes[1];
    const int nF      = in_sizes[0];
    const int dim_in  = nF / BATCH;
    const int dim_out = out_size / BATCH;

    int*   rstart = (int*)d_ws;
    int*   rend   = rstart + dim_out;
    float* fT     = (float*)(rend + dim_out);

    const int use_main = (dim_in <= DIN_CAP) &&
                         (ws_size >= (size_t)(2 * dim_out) * 4 + (size_t)nF * 4);

    const int ctiles = (dim_in + 31) / 32;
    const int TB = use_main ? ctiles * (BATCH / 32) : 0;
    const int NB = (nnz + 255) / 256;
    prep_t<<<TB + NB, 256, 0, stream>>>(f, rows, rstart, rend, fT,
                                        nnz, dim_in, TB, ctiles);

    if (use_main) {
        dim3 grid((dim_out + 255) / 256, YSPLIT);   // ~996 blocks: one generation
        tsq_main<<<grid, 256, 0, stream>>>(fT, vals, ci, cj, rstart, rend, out,
                                           dim_in, dim_out, nnz);
    } else {
        dim3 grid((dim_out + 255) / 256, BATCH);
        tsq_fallback<<<grid, 256, 0, stream>>>(f, vals, ci, cj, rstart, rend,
                                               out, dim_in, dim_out, nnz);
    }
}